// Round 18
// baseline (77.773 us; speedup 1.0000x reference)
//
#include <hip/hip_runtime.h>
#include <hip/hip_bf16.h>

// out[e,i] = sum_j (e@W1+b1)[e, i*16+j] * h[e,j]  +  (e@W2+b2)[e,i]
// One fp16 MFMA GEMM over K=576 per 16-edge tile (18x mfma_f32_16x16x32_f16).
// K-mapping (same placement function on A and B sides):
//   main block kk=0..15, slot s=(lane>>4)*8+t:  (d=s, j=kk)
//     A[r,s] = e[edge_r, s] * h[edge_r, kk]     B[s, i=r] = W1[s*256 + r*16 + kk]
//   block 16: A = e[edge, s],                   B = W2[s*16 + r]
//   block 17: s<16: A=h[edge,s], B=b1[r*16+s]; s==16: A=1, B=b2[r]; else 0
//     -> block-17 A is free: hP0-3 (g=0), hP4-7 (g=1), {1,0..} (g=2), 0 (g=3)
// R17 = R16 (nt stores, 77.3us) + Fb rotation depth 4: each ds_read_b128 is
//   issued ~3 MFMAs (~50cyc) before its consumer vs ~120cyc ds latency (m117),
//   cutting the ~16 partial lgkm stalls/tile. Costs +8 VGPR -> 72 (4-wave
//   class, known ~2.4us penalty from R12 A/B); pays if ds-latency share > that.
// NO launch_bounds min-waves (R7 spill), NO local arrays (R2 PromoteAlloca).

using f16x8  = __attribute__((ext_vector_type(8))) _Float16;
using f16x2  = __attribute__((ext_vector_type(2))) _Float16;
using fp16v2 = __attribute__((ext_vector_type(2))) __fp16;   // native cvt_pkrtz type
using f32x4  = __attribute__((ext_vector_type(4))) float;
using u32x4  = __attribute__((ext_vector_type(4))) unsigned int;

static __device__ __forceinline__ unsigned int pkrtz(float lo, float hi) {
    fp16v2 p = __builtin_amdgcn_cvt_pkrtz(lo, hi);
    return __builtin_bit_cast(unsigned int, p);
}
static __device__ __forceinline__ f16x2 u2h(unsigned int u) {
    return __builtin_bit_cast(f16x2, u);
}
static __device__ __forceinline__ unsigned int h2u(f16x2 h) {
    return __builtin_bit_cast(unsigned int, h);
}
static __device__ __forceinline__ unsigned short f2h_bits(float x) {
    _Float16 h = (_Float16)x;                 // RNE scalar cast (one-time build only)
    return __builtin_bit_cast(unsigned short, h);
}
static __device__ __forceinline__ unsigned int bperm(int baddr, unsigned int src) {
    return (unsigned int)__builtin_amdgcn_ds_bpermute(baddr, (int)src);
}

__global__ void __launch_bounds__(256) msg_kernel(
    const float* __restrict__ hptr, const float* __restrict__ eptr,
    const float* __restrict__ W1,   const float* __restrict__ b1,
    const float* __restrict__ W2,   const float* __restrict__ b2,
    float* __restrict__ out, int E)
{
    // B fragment store: [kk=0..17][lane=0..63][t=0..7] fp16, 18 KB.
    __shared__ __align__(16) unsigned short Bs[18 * 64 * 8];

    const int lane = threadIdx.x & 63;
    const int g    = lane >> 4;        // K-group (0..3); lane's d-range = [g*8, g*8+8)
    const int r    = lane & 15;        // A row (edge-in-tile) == B/D col (output i)
    const int wv   = threadIdx.x >> 6; // wave id: parallel B-build by t-pair

    // ---- build B in LDS: wave wv handles t = wv*2, wv*2+1 ----
    #pragma unroll
    for (int tq = 0; tq < 2; ++tq) {
        const int t = wv * 2 + tq;
        const int d = g * 8 + t;
        const float4* wp = (const float4*)(W1 + (size_t)d * 256 + r * 16);
        const float4 w0 = wp[0], w1 = wp[1], w2 = wp[2], w3 = wp[3];
        Bs[( 0*64 + lane)*8 + t] = f2h_bits(w0.x);
        Bs[( 1*64 + lane)*8 + t] = f2h_bits(w0.y);
        Bs[( 2*64 + lane)*8 + t] = f2h_bits(w0.z);
        Bs[( 3*64 + lane)*8 + t] = f2h_bits(w0.w);
        Bs[( 4*64 + lane)*8 + t] = f2h_bits(w1.x);
        Bs[( 5*64 + lane)*8 + t] = f2h_bits(w1.y);
        Bs[( 6*64 + lane)*8 + t] = f2h_bits(w1.z);
        Bs[( 7*64 + lane)*8 + t] = f2h_bits(w1.w);
        Bs[( 8*64 + lane)*8 + t] = f2h_bits(w2.x);
        Bs[( 9*64 + lane)*8 + t] = f2h_bits(w2.y);
        Bs[(10*64 + lane)*8 + t] = f2h_bits(w2.z);
        Bs[(11*64 + lane)*8 + t] = f2h_bits(w2.w);
        Bs[(12*64 + lane)*8 + t] = f2h_bits(w3.x);
        Bs[(13*64 + lane)*8 + t] = f2h_bits(w3.y);
        Bs[(14*64 + lane)*8 + t] = f2h_bits(w3.z);
        Bs[(15*64 + lane)*8 + t] = f2h_bits(w3.w);
        Bs[(16*64 + lane)*8 + t] = f2h_bits(W2[d * 16 + r]);
        float v;
        if (d < 16)       v = b1[r * 16 + d];
        else if (d == 16) v = b2[r];
        else              v = 0.0f;
        Bs[(17*64 + lane)*8 + t] = f2h_bits(v);
    }
    __syncthreads();   // only barrier in the kernel

    const int ntiles = (E + 15) >> 4;
    const int nwaves = (gridDim.x * blockDim.x) >> 6;
    const int wid    = (blockIdx.x * blockDim.x + threadIdx.x) >> 6;
    if (wid >= ntiles) return;

    const unsigned short* bsl = &Bs[lane * 8];   // per-lane base; block kk at +kk*512

    // bpermute byte-addresses of the 4 lanes holding row r's h quarters
    const int ba0 = (r      ) << 2;
    const int ba1 = (r + 16 ) << 2;
    const int ba2 = (r + 32 ) << 2;
    const int ba3 = (r + 48 ) << 2;

#define LDSB(KK) __builtin_bit_cast(f16x8, *reinterpret_cast<const u32x4*>(bsl + (KK) * 512))

    // 3 loads per tile: e (2x float4, lane's own 8 values), h (1x float4, quarter)
#define LOADT(T, E0, E1, H0) { \
        int tt = (T); if (tt >= ntiles) tt = ntiles - 1; \
        int cc = tt * 16 + r; if (cc >= E) cc = E - 1; \
        const float4* ep_ = (const float4*)(eptr + (size_t)cc * 32 + g * 8); \
        E0 = ep_[0]; E1 = ep_[1]; \
        H0 = *(const float4*)(hptr + (size_t)cc * 16 + g * 4); }

    // MB: broadcast one fp16 from packed pair (static HALF -> VOP3P op_sel),
    // 4x v_pk_mul_f16, 1 MFMA with rotated B fragment.
#define MB(HPQ, HALF, BF, ACC) { \
        const f16x2 hv_ = u2h(HPQ); \
        const f16x2 hh_ = {hv_[HALF], hv_[HALF]}; \
        u32x4 u_ = {h2u(hh_ * u2h(eP0)), h2u(hh_ * u2h(eP1)), \
                    h2u(hh_ * u2h(eP2)), h2u(hh_ * u2h(eP3))}; \
        ACC = __builtin_amdgcn_mfma_f32_16x16x32_f16( \
            __builtin_bit_cast(f16x8, u_), BF, ACC, 0, 0, 0); }

    // ---- 1-stage pipeline, Fb rotation depth 4 ----
    float4 sE0, sE1, sH;
    int t = wid;
    LOADT(t, sE0, sE1, sH);

    while (true) {
        // B-frag preload (depth-4 rotation: each read ~3 MFMAs ahead of use)
        f16x8 Fb0 = LDSB(0), Fb1 = LDSB(1), Fb2 = LDSB(2), Fb3 = LDSB(3);

        // convert staged f32 -> packed fp16 (waits on this tile's loads)
        const unsigned int eP0 = pkrtz(sE0.x, sE0.y), eP1 = pkrtz(sE0.z, sE0.w);
        const unsigned int eP2 = pkrtz(sE1.x, sE1.y), eP3 = pkrtz(sE1.z, sE1.w);
        const unsigned int hQ0 = pkrtz(sH.x, sH.y),   hQ1 = pkrtz(sH.z, sH.w);

        // staging regs consumed -> immediately issue next tile's loads
        LOADT(t + nwaves, sE0, sE1, sH);

        // rebuild full packed h row via crossbar pulls from the row's 4 lanes
        const unsigned int hP0 = bperm(ba0, hQ0), hP1 = bperm(ba0, hQ1);
        const unsigned int hP2 = bperm(ba1, hQ0), hP3 = bperm(ba1, hQ1);
        const unsigned int hP4 = bperm(ba2, hQ0), hP5 = bperm(ba2, hQ1);
        const unsigned int hP6 = bperm(ba3, hQ0), hP7 = bperm(ba3, hQ1);

        f32x4 acc0 = {0.0f, 0.0f, 0.0f, 0.0f};
        f32x4 acc1 = {0.0f, 0.0f, 0.0f, 0.0f};

        MB(hP0, 0, Fb0, acc0)  Fb0 = LDSB( 4);
        MB(hP0, 1, Fb1, acc1)  Fb1 = LDSB( 5);
        MB(hP1, 0, Fb2, acc0)  Fb2 = LDSB( 6);
        MB(hP1, 1, Fb3, acc1)  Fb3 = LDSB( 7);
        MB(hP2, 0, Fb0, acc0)  Fb0 = LDSB( 8);
        MB(hP2, 1, Fb1, acc1)  Fb1 = LDSB( 9);
        MB(hP3, 0, Fb2, acc0)  Fb2 = LDSB(10);
        MB(hP3, 1, Fb3, acc1)  Fb3 = LDSB(11);
        MB(hP4, 0, Fb0, acc0)  Fb0 = LDSB(12);
        MB(hP4, 1, Fb1, acc1)  Fb1 = LDSB(13);
        MB(hP5, 0, Fb2, acc0)  Fb2 = LDSB(14);
        MB(hP5, 1, Fb3, acc1)  Fb3 = LDSB(15);
        MB(hP6, 0, Fb0, acc0)  Fb0 = LDSB(16);
        MB(hP6, 1, Fb1, acc1)  Fb1 = LDSB(17);
        MB(hP7, 0, Fb2, acc0)
        MB(hP7, 1, Fb3, acc1)

        {   // block 16: A = packed e
            u32x4 u_ = {eP0, eP1, eP2, eP3};
            acc0 = __builtin_amdgcn_mfma_f32_16x16x32_f16(
                __builtin_bit_cast(f16x8, u_), Fb0, acc0, 0, 0, 0);
        }
        {   // block 17: A = hP0-3 (g=0) / hP4-7 (g=1) / {1,0,..} (g=2) / 0 (g=3)
            const unsigned int a0 = (g == 0) ? hP0 : (g == 1) ? hP4
                                   : (g == 2) ? 0x00003C00u : 0u;
            const unsigned int a1 = (g == 0) ? hP1 : (g == 1) ? hP5 : 0u;
            const unsigned int a2 = (g == 0) ? hP2 : (g == 1) ? hP6 : 0u;
            const unsigned int a3 = (g == 0) ? hP3 : (g == 1) ? hP7 : 0u;
            u32x4 u_ = {a0, a1, a2, a3};
            acc1 = __builtin_amdgcn_mfma_f32_16x16x32_f16(
                __builtin_bit_cast(f16x8, u_), Fb1, acc1, 0, 0, 0);
        }

        // D: col = r = i, row = g*4 + q = edge-in-tile. NON-TEMPORAL stores.
        const int rowbase = t * 16 + g * 4;
        float* op = out + (size_t)rowbase * 16 + r;
        const float s0 = acc0[0] + acc1[0], s1 = acc0[1] + acc1[1];
        const float s2 = acc0[2] + acc1[2], s3 = acc0[3] + acc1[3];
        if (rowbase + 3 < E) {
            __builtin_nontemporal_store(s0, op);
            __builtin_nontemporal_store(s1, op + 16);
            __builtin_nontemporal_store(s2, op + 32);
            __builtin_nontemporal_store(s3, op + 48);
        } else {
            if (rowbase     < E) __builtin_nontemporal_store(s0, op);
            if (rowbase + 1 < E) __builtin_nontemporal_store(s1, op + 16);
            if (rowbase + 2 < E) __builtin_nontemporal_store(s2, op + 32);
        }

        t += nwaves;
        if (t >= ntiles) break;
    }

#undef MB
#undef LOADT
#undef LDSB
}

extern "C" void kernel_launch(void* const* d_in, const int* in_sizes, int n_in,
                              void* d_out, int out_size, void* d_ws, size_t ws_size,
                              hipStream_t stream) {
    const float* h  = (const float*)d_in[0];
    const float* e  = (const float*)d_in[1];
    const float* W1 = (const float*)d_in[2];
    const float* b1 = (const float*)d_in[3];
    const float* W2 = (const float*)d_in[4];
    const float* b2 = (const float*)d_in[5];
    float* out = (float*)d_out;

    const int E = in_sizes[0] / 16;   // h is [E,16]

    dim3 grid(2048), block(256);
    hipLaunchKernelGGL(msg_kernel, grid, block, 0, stream,
                       h, e, W1, b1, W2, b2, out, E);
}

// Round 19
// 77.760 us; speedup vs baseline: 1.0002x; 1.0002x over previous
//
#include <hip/hip_runtime.h>
#include <hip/hip_bf16.h>

// out[e,i] = sum_j (e@W1+b1)[e, i*16+j] * h[e,j]  +  (e@W2+b2)[e,i]
// fp16 MFMA GEMM over K=576 per 16-edge tile (18x mfma_f32_16x16x32_f16).
// K-mapping: main block kk=0..15, slot s=(lane>>4)*8+t: (d=s, j=kk)
//   A[r,s]=e[edge_r,s]*h[edge_r,kk]  B[s,i=r]=W1[s*256+r*16+kk]
//   blk16: A=e[edge,s], B=W2[s*16+r]; blk17: A=h/1/0, B=b1/b2 (see R11).
// R18 = R16 (nt stores, 77.3us) + TWO adjacent tiles per iteration sharing
//   each B-fragment ds_read: 36->18 ds_read_b128/pair on the ~50%-busy LDS
//   pipe (the 18 reads/tile re-fetch LOOP-INVARIANT data; R15 showed regs
//   can't hold them at 64-VGPR class). Loop overhead also halves.
// NO launch_bounds min-waves (R7 spill), NO local arrays (R2 PromoteAlloca).

using f16x8  = __attribute__((ext_vector_type(8))) _Float16;
using f16x2  = __attribute__((ext_vector_type(2))) _Float16;
using fp16v2 = __attribute__((ext_vector_type(2))) __fp16;
using f32x4  = __attribute__((ext_vector_type(4))) float;
using u32x4  = __attribute__((ext_vector_type(4))) unsigned int;

static __device__ __forceinline__ unsigned int pkrtz(float lo, float hi) {
    fp16v2 p = __builtin_amdgcn_cvt_pkrtz(lo, hi);
    return __builtin_bit_cast(unsigned int, p);
}
static __device__ __forceinline__ f16x2 u2h(unsigned int u) {
    return __builtin_bit_cast(f16x2, u);
}
static __device__ __forceinline__ unsigned int h2u(f16x2 h) {
    return __builtin_bit_cast(unsigned int, h);
}
static __device__ __forceinline__ unsigned short f2h_bits(float x) {
    _Float16 h = (_Float16)x;
    return __builtin_bit_cast(unsigned short, h);
}
static __device__ __forceinline__ unsigned int bperm(int baddr, unsigned int src) {
    return (unsigned int)__builtin_amdgcn_ds_bpermute(baddr, (int)src);
}

__global__ void __launch_bounds__(256) msg_kernel(
    const float* __restrict__ hptr, const float* __restrict__ eptr,
    const float* __restrict__ W1,   const float* __restrict__ b1,
    const float* __restrict__ W2,   const float* __restrict__ b2,
    float* __restrict__ out, int E)
{
    __shared__ __align__(16) unsigned short Bs[18 * 64 * 8];

    const int lane = threadIdx.x & 63;
    const int g    = lane >> 4;
    const int r    = lane & 15;
    const int wv   = threadIdx.x >> 6;

    // ---- build B in LDS: wave wv handles t = wv*2, wv*2+1 ----
    #pragma unroll
    for (int tq = 0; tq < 2; ++tq) {
        const int t = wv * 2 + tq;
        const int d = g * 8 + t;
        const float4* wp = (const float4*)(W1 + (size_t)d * 256 + r * 16);
        const float4 w0 = wp[0], w1 = wp[1], w2 = wp[2], w3 = wp[3];
        Bs[( 0*64 + lane)*8 + t] = f2h_bits(w0.x);
        Bs[( 1*64 + lane)*8 + t] = f2h_bits(w0.y);
        Bs[( 2*64 + lane)*8 + t] = f2h_bits(w0.z);
        Bs[( 3*64 + lane)*8 + t] = f2h_bits(w0.w);
        Bs[( 4*64 + lane)*8 + t] = f2h_bits(w1.x);
        Bs[( 5*64 + lane)*8 + t] = f2h_bits(w1.y);
        Bs[( 6*64 + lane)*8 + t] = f2h_bits(w1.z);
        Bs[( 7*64 + lane)*8 + t] = f2h_bits(w1.w);
        Bs[( 8*64 + lane)*8 + t] = f2h_bits(w2.x);
        Bs[( 9*64 + lane)*8 + t] = f2h_bits(w2.y);
        Bs[(10*64 + lane)*8 + t] = f2h_bits(w2.z);
        Bs[(11*64 + lane)*8 + t] = f2h_bits(w2.w);
        Bs[(12*64 + lane)*8 + t] = f2h_bits(w3.x);
        Bs[(13*64 + lane)*8 + t] = f2h_bits(w3.y);
        Bs[(14*64 + lane)*8 + t] = f2h_bits(w3.z);
        Bs[(15*64 + lane)*8 + t] = f2h_bits(w3.w);
        Bs[(16*64 + lane)*8 + t] = f2h_bits(W2[d * 16 + r]);
        float v;
        if (d < 16)       v = b1[r * 16 + d];
        else if (d == 16) v = b2[r];
        else              v = 0.0f;
        Bs[(17*64 + lane)*8 + t] = f2h_bits(v);
    }
    __syncthreads();

    const int ntiles = (E + 15) >> 4;
    const int npairs = (ntiles + 1) >> 1;
    const int nwaves = (gridDim.x * blockDim.x) >> 6;
    const int wid    = (blockIdx.x * blockDim.x + threadIdx.x) >> 6;
    if (wid >= npairs) return;

    const unsigned short* bsl = &Bs[lane * 8];

    const int ba0 = (r      ) << 2;
    const int ba1 = (r + 16 ) << 2;
    const int ba2 = (r + 32 ) << 2;
    const int ba3 = (r + 48 ) << 2;

#define LDSB(KK) __builtin_bit_cast(f16x8, *reinterpret_cast<const u32x4*>(bsl + (KK) * 512))

    // load both tiles of pair P (tiles 2P, 2P+1): 6 loads
#define LOADP(P, AE0, AE1, AH, BE0, BE1, BH) { \
        int pp = (P); if (pp >= npairs) pp = npairs - 1; \
        int t1_ = pp * 2 + 1; if (t1_ >= ntiles) t1_ = ntiles - 1; \
        int c0_ = pp * 2 * 16 + r; if (c0_ >= E) c0_ = E - 1; \
        int c1_ = t1_ * 16 + r;    if (c1_ >= E) c1_ = E - 1; \
        const float4* eA_ = (const float4*)(eptr + (size_t)c0_ * 32 + g * 8); \
        AE0 = eA_[0]; AE1 = eA_[1]; \
        AH  = *(const float4*)(hptr + (size_t)c0_ * 16 + g * 4); \
        const float4* eB_ = (const float4*)(eptr + (size_t)c1_ * 32 + g * 8); \
        BE0 = eB_[0]; BE1 = eB_[1]; \
        BH  = *(const float4*)(hptr + (size_t)c1_ * 16 + g * 4); }

#define MB(HPQ, HALF, FB, ACC, EP0, EP1, EP2, EP3) { \
        const f16x2 hv_ = u2h(HPQ); \
        const f16x2 hh_ = {hv_[HALF], hv_[HALF]}; \
        u32x4 u_ = {h2u(hh_ * u2h(EP0)), h2u(hh_ * u2h(EP1)), \
                    h2u(hh_ * u2h(EP2)), h2u(hh_ * u2h(EP3))}; \
        ACC = __builtin_amdgcn_mfma_f32_16x16x32_f16( \
            __builtin_bit_cast(f16x8, u_), FB, ACC, 0, 0, 0); }

    // one q-block: 4 bperm pulls (2/tile), 4 shared Fb reads, 8 MFMAs
#define QBLK(BA, K0) { \
        const unsigned int hALo = bperm(BA, hQA0), hAHi = bperm(BA, hQA1); \
        const unsigned int hBLo = bperm(BA, hQB0), hBHi = bperm(BA, hQB1); \
        f16x8 Fb_; \
        Fb_ = LDSB(K0    ); MB(hALo, 0, Fb_, accA0, eAP0,eAP1,eAP2,eAP3) \
                            MB(hBLo, 0, Fb_, accB0, eBP0,eBP1,eBP2,eBP3) \
        Fb_ = LDSB(K0 + 1); MB(hALo, 1, Fb_, accA1, eAP0,eAP1,eAP2,eAP3) \
                            MB(hBLo, 1, Fb_, accB1, eBP0,eBP1,eBP2,eBP3) \
        Fb_ = LDSB(K0 + 2); MB(hAHi, 0, Fb_, accA0, eAP0,eAP1,eAP2,eAP3) \
                            MB(hBHi, 0, Fb_, accB0, eBP0,eBP1,eBP2,eBP3) \
        Fb_ = LDSB(K0 + 3); MB(hAHi, 1, Fb_, accA1, eAP0,eAP1,eAP2,eAP3) \
                            MB(hBHi, 1, Fb_, accB1, eBP0,eBP1,eBP2,eBP3) }

    float4 aE0, aE1, aH, bE0, bE1, bH;
    int p = wid;
    LOADP(p, aE0, aE1, aH, bE0, bE1, bH);

    while (true) {
        // convert staged pair -> packed fp16
        const unsigned int eAP0 = pkrtz(aE0.x, aE0.y), eAP1 = pkrtz(aE0.z, aE0.w);
        const unsigned int eAP2 = pkrtz(aE1.x, aE1.y), eAP3 = pkrtz(aE1.z, aE1.w);
        const unsigned int hQA0 = pkrtz(aH.x, aH.y),   hQA1 = pkrtz(aH.z, aH.w);
        const unsigned int eBP0 = pkrtz(bE0.x, bE0.y), eBP1 = pkrtz(bE0.z, bE0.w);
        const unsigned int eBP2 = pkrtz(bE1.x, bE1.y), eBP3 = pkrtz(bE1.z, bE1.w);
        const unsigned int hQB0 = pkrtz(bH.x, bH.y),   hQB1 = pkrtz(bH.z, bH.w);

        // staging consumed -> prefetch next pair
        LOADP(p + nwaves, aE0, aE1, aH, bE0, bE1, bH);

        f32x4 accA0 = {0.0f, 0.0f, 0.0f, 0.0f};
        f32x4 accA1 = {0.0f, 0.0f, 0.0f, 0.0f};
        f32x4 accB0 = {0.0f, 0.0f, 0.0f, 0.0f};
        f32x4 accB1 = {0.0f, 0.0f, 0.0f, 0.0f};

        QBLK(ba0,  0)
        QBLK(ba1,  4)
        QBLK(ba2,  8)
        QBLK(ba3, 12)

        {   // block 16 (shared Fb): A = packed e
            const f16x8 Fb_ = LDSB(16);
            u32x4 uA_ = {eAP0, eAP1, eAP2, eAP3};
            accA0 = __builtin_amdgcn_mfma_f32_16x16x32_f16(
                __builtin_bit_cast(f16x8, uA_), Fb_, accA0, 0, 0, 0);
            u32x4 uB_ = {eBP0, eBP1, eBP2, eBP3};
            accB0 = __builtin_amdgcn_mfma_f32_16x16x32_f16(
                __builtin_bit_cast(f16x8, uB_), Fb_, accB0, 0, 0, 0);
        }
        {   // block 17 (shared Fb): A = h slots (g<2), {1,0..} (g==2), 0 (g==3)
            const int bx0 = (g == 1) ? ba2 : ba0;
            const int bx1 = (g == 1) ? ba3 : ba1;
            unsigned int aA0 = bperm(bx0, hQA0), aA1 = bperm(bx0, hQA1);
            unsigned int aA2 = bperm(bx1, hQA0), aA3 = bperm(bx1, hQA1);
            unsigned int aB0 = bperm(bx0, hQB0), aB1 = bperm(bx0, hQB1);
            unsigned int aB2 = bperm(bx1, hQB0), aB3 = bperm(bx1, hQB1);
            if (g >= 2) {
                const unsigned int one = (g == 2) ? 0x00003C00u : 0u;
                aA0 = one; aA1 = 0u; aA2 = 0u; aA3 = 0u;
                aB0 = one; aB1 = 0u; aB2 = 0u; aB3 = 0u;
            }
            const f16x8 Fb_ = LDSB(17);
            u32x4 uA_ = {aA0, aA1, aA2, aA3};
            accA1 = __builtin_amdgcn_mfma_f32_16x16x32_f16(
                __builtin_bit_cast(f16x8, uA_), Fb_, accA1, 0, 0, 0);
            u32x4 uB_ = {aB0, aB1, aB2, aB3};
            accB1 = __builtin_amdgcn_mfma_f32_16x16x32_f16(
                __builtin_bit_cast(f16x8, uB_), Fb_, accB1, 0, 0, 0);
        }

        // stores (non-temporal), both tiles
        {
            const int t0s = p * 2;
            int t1s = t0s + 1; if (t1s >= ntiles) t1s = ntiles - 1;
            const int rbA = t0s * 16 + g * 4;
            float* opA = out + (size_t)rbA * 16 + r;
            const float sA0 = accA0[0] + accA1[0], sA1 = accA0[1] + accA1[1];
            const float sA2 = accA0[2] + accA1[2], sA3 = accA0[3] + accA1[3];
            if (rbA + 3 < E) {
                __builtin_nontemporal_store(sA0, opA);
                __builtin_nontemporal_store(sA1, opA + 16);
                __builtin_nontemporal_store(sA2, opA + 32);
                __builtin_nontemporal_store(sA3, opA + 48);
            } else {
                if (rbA     < E) __builtin_nontemporal_store(sA0, opA);
                if (rbA + 1 < E) __builtin_nontemporal_store(sA1, opA + 16);
                if (rbA + 2 < E) __builtin_nontemporal_store(sA2, opA + 32);
            }
            const int rbB = t1s * 16 + g * 4;
            float* opB = out + (size_t)rbB * 16 + r;
            const float sB0 = accB0[0] + accB1[0], sB1 = accB0[1] + accB1[1];
            const float sB2 = accB0[2] + accB1[2], sB3 = accB0[3] + accB1[3];
            if (rbB + 3 < E) {
                __builtin_nontemporal_store(sB0, opB);
                __builtin_nontemporal_store(sB1, opB + 16);
                __builtin_nontemporal_store(sB2, opB + 32);
                __builtin_nontemporal_store(sB3, opB + 48);
            } else {
                if (rbB     < E) __builtin_nontemporal_store(sB0, opB);
                if (rbB + 1 < E) __builtin_nontemporal_store(sB1, opB + 16);
                if (rbB + 2 < E) __builtin_nontemporal_store(sB2, opB + 32);
            }
        }

        p += nwaves;
        if (p >= npairs) break;
    }

#undef QBLK
#undef MB
#undef LOADP
#undef LDSB
}

extern "C" void kernel_launch(void* const* d_in, const int* in_sizes, int n_in,
                              void* d_out, int out_size, void* d_ws, size_t ws_size,
                              hipStream_t stream) {
    const float* h  = (const float*)d_in[0];
    const float* e  = (const float*)d_in[1];
    const float* W1 = (const float*)d_in[2];
    const float* b1 = (const float*)d_in[3];
    const float* W2 = (const float*)d_in[4];
    const float* b2 = (const float*)d_in[5];
    float* out = (float*)d_out;

    const int E = in_sizes[0] / 16;   // h is [E,16]

    dim3 grid(2048), block(256);
    hipLaunchKernelGGL(msg_kernel, grid, block, 0, stream,
                       h, e, W1, b1, W2, b2, out, E);
}